// Round 14
// baseline (323.114 us; speedup 1.0000x reference)
//
#include <hip/hip_runtime.h>
#include <math.h>

#define BB 8
#define NN 8192
#define CC 64
#define FE 32
#define KN 16
#define CP3 67
#define QPW 8                 // queries per wave (z-adjacent)
#define WPB 4                 // waves per block
#define CAPQ 64               // per-query stack (count-checked => exact)
#define ZBINS 256

// Device-global scratch (module .bss). All bytes written every launch before read.
__device__ float g_wsf[128];                  // scale[64], shift[64]
__device__ float g_feat0[BB * NN * FE];       // 8 MB
__device__ int   g_idx[BB * NN * KN];         // 4 MB
__device__ float4 g_sorted[BB * NN];          // z-bin-sorted {x,y,z,xx}
__device__ int    g_sorig[BB * NN];           // sorted -> original index
__device__ unsigned g_binoff[BB * (ZBINS + 1)];

// Identical in k_zbin and k_knn (same source => same bits; monotone in z).
__device__ __forceinline__ int zbin(float z) {
    int bi = (int)((z + 6.0f) * (64.0f / 3.0f));   // 256 bins over [-6,6]
    if (bi < 0) bi = 0;
    if (bi > ZBINS - 1) bi = ZBINS - 1;
    return bi;
}
// FROZEN reference xx (verified R5, XLA-CPU FMA contraction)
__device__ __forceinline__ float frz_xx(float x, float y, float z) {
    return __fmaf_rn(z, z, __fmaf_rn(y, y, __fmul_rn(x, x)));
}

// ---------------- kernel 1: BN stats -> scale/shift ----------------
__global__ __launch_bounds__(1024) void k_bnstats(const float* __restrict__ feat,
        const float* __restrict__ gamma, const float* __restrict__ beta) {
    int c = blockIdx.x;
    int tid = threadIdx.x;
    double s = 0.0, s2 = 0.0;
    for (int b = 0; b < BB; ++b) {
        const float* p = feat + ((size_t)(b * CC + c)) * NN;
        for (int n = tid; n < NN; n += 1024) {
            double v = (double)p[n];
            s += v; s2 += v * v;
        }
    }
    __shared__ double sh[1024], sh2[1024];
    sh[tid] = s; sh2[tid] = s2;
    __syncthreads();
    for (int off = 512; off > 0; off >>= 1) {
        if (tid < off) { sh[tid] += sh[tid + off]; sh2[tid] += sh2[tid + off]; }
        __syncthreads();
    }
    if (tid == 0) {
        double inv = 1.0 / (double)(BB * NN);
        double mean = sh[0] * inv;
        double var = sh2[0] * inv - mean * mean;
        float sc = gamma[c] * (float)(1.0 / sqrt(var + (double)1e-5f));
        g_wsf[c] = sc;
        g_wsf[64 + c] = beta[c] - sc * (float)mean;
    }
}

// ---------------- kernel 1b: z-binning (histogram + scatter) --------------
__global__ __launch_bounds__(1024) void k_zbin(const float* __restrict__ xyz) {
    __shared__ unsigned hist[ZBINS];
    __shared__ unsigned boff[ZBINS + 1];
    int b = blockIdx.x;
    int tid = threadIdx.x;
    if (tid < ZBINS) hist[tid] = 0;
    __syncthreads();
    const float* bx = xyz + (size_t)b * NN * 3;
    for (int n = tid; n < NN; n += 1024)
        atomicAdd(&hist[zbin(bx[n * 3 + 2])], 1u);
    __syncthreads();
    if (tid == 0) {
        unsigned s = 0;
        for (int i = 0; i < ZBINS; ++i) { boff[i] = s; s += hist[i]; }
        boff[ZBINS] = s;
    }
    __syncthreads();
    if (tid < ZBINS) hist[tid] = 0;            // reuse as cursors
    if (tid < ZBINS + 1) g_binoff[b * (ZBINS + 1) + tid] = boff[tid];
    __syncthreads();
    for (int n = tid; n < NN; n += 1024) {
        const float* p = bx + (size_t)n * 3;
        float x = p[0], y = p[1], z = p[2];
        unsigned pos = boff[zbin(z)] + atomicAdd(&hist[zbin(z)], 1u);
        g_sorted[(size_t)b * NN + pos] = make_float4(x, y, z, frz_xx(x, y, z));
        g_sorig[(size_t)b * NN + pos] = n;
    }
}

// ---------------- kernel 2: feat0 = Wg' * [feat;xyz] + bias0 ----------------
__global__ __launch_bounds__(256) void k_feat0(const float* __restrict__ feat,
        const float* __restrict__ xyz, const float* __restrict__ Wg) {
    __shared__ float wgs[CP3 * FE];
    __shared__ float bias0[FE];
    int tid = threadIdx.x;
    for (int i = tid; i < CP3 * FE; i += 256) {
        int c = i >> 5, e = i & 31;
        float w = Wg[e * CP3 + c];
        if (c < CC) w *= g_wsf[c];
        wgs[c * FE + e] = w;
    }
    if (tid < FE) {
        float sacc = 0.f;
        for (int c = 0; c < CC; ++c) sacc = fmaf(Wg[tid * CP3 + c], g_wsf[64 + c], sacc);
        bias0[tid] = sacc;
    }
    __syncthreads();
    int b = blockIdx.x >> 5;
    int n = ((blockIdx.x & 31) << 8) + tid;
    const float* pz = xyz + ((size_t)(b * NN + n)) * 3;
    float x = pz[0], y = pz[1], z = pz[2];

    float acc[FE];
    #pragma unroll
    for (int e = 0; e < FE; ++e) acc[e] = bias0[e];
    const float* fp = feat + (size_t)b * CC * NN + n;
    for (int c = 0; c < CC; ++c) {
        float v = fp[(size_t)c * NN];
        const float4* w4 = (const float4*)(wgs + c * FE);
        #pragma unroll
        for (int e0 = 0; e0 < 8; ++e0) {
            float4 w = w4[e0];
            acc[e0 * 4 + 0] = fmaf(w.x, v, acc[e0 * 4 + 0]);
            acc[e0 * 4 + 1] = fmaf(w.y, v, acc[e0 * 4 + 1]);
            acc[e0 * 4 + 2] = fmaf(w.z, v, acc[e0 * 4 + 2]);
            acc[e0 * 4 + 3] = fmaf(w.w, v, acc[e0 * 4 + 3]);
        }
    }
    #pragma unroll
    for (int d = 0; d < 3; ++d) {
        float v = (d == 0) ? x : ((d == 1) ? y : z);
        const float4* w4 = (const float4*)(wgs + (CC + d) * FE);
        #pragma unroll
        for (int e0 = 0; e0 < 8; ++e0) {
            float4 w = w4[e0];
            acc[e0 * 4 + 0] = fmaf(w.x, v, acc[e0 * 4 + 0]);
            acc[e0 * 4 + 1] = fmaf(w.y, v, acc[e0 * 4 + 1]);
            acc[e0 * 4 + 2] = fmaf(w.z, v, acc[e0 * 4 + 2]);
            acc[e0 * 4 + 3] = fmaf(w.w, v, acc[e0 * 4 + 3]);
        }
    }
    float4* outp = (float4*)(g_feat0 + ((size_t)(b * NN + n)) * FE);
    #pragma unroll
    for (int e0 = 0; e0 < 8; ++e0)
        outp[e0] = make_float4(acc[e0 * 4 + 0], acc[e0 * 4 + 1], acc[e0 * 4 + 2], acc[e0 * 4 + 3]);
}

// ---------------- kernel 3: autonomous-wave z-windowed KNN ---------------
// FROZEN reference arithmetic (verified R5):
//   dot  = fma(zq,zm, fma(yq,ym, xq*xm))
//   dist = fadd( fma(-2, dot, xx_q), xx_m )
// One wave owns 8 z-adjacent queries; no __syncthreads, no LDS atomics.
// Exactness: accept iff 16 <= cnt <= CAPQ (stack then holds ALL gate
// passers; z-window [zq-R,zq+R], R=sqrt(t0+1e-3)+1e-3 (+-1 bin) covers the
// gate set). Threshold search: bracketed geometric bisection (R12-proven).
// Selection: counting-rank (R13-proven). NEW (R14): wave->query-group
// mapping decorrelated from z-rank via odd-multiplier bijection -- R13's
// contiguous mapping put all fat (z-center) windows on the same CUs, so
// dispatch-average occupancy collapsed to 19% (7x window-mass spread);
// interleaving flattens per-CU work.
__global__ __launch_bounds__(256) void k_knn() {
    __shared__ unsigned long long qbuf[WPB * QPW * CAPQ];   // 16 KB
    int tid = threadIdx.x;
    int lane = tid & 63;
    int w = tid >> 6;
    int wid = blockIdx.x * WPB + w;             // 0..8191
    wid = (wid * 421) & 8191;                   // bijective z-rank interleave
    int b = wid >> 10;                          // 1024 waves per batch
    int n0 = (wid & 1023) * QPW;
    const float4* S = g_sorted + (size_t)b * NN;
    const int* SO = g_sorig + (size_t)b * NN;
    const unsigned* BO = g_binoff + b * (ZBINS + 1);
    unsigned long long lt = (1ull << lane) - 1ull;

    float qx[QPW], qy[QPW], qz[QPW], qxx[QPW], t0[QPW], tlo[QPW], thi[QPW];
    int qorig[QPW];
    unsigned cnt[QPW];
    bool qdone[QPW];
    #pragma unroll
    for (int i = 0; i < QPW; ++i) {
        float4 qv = S[n0 + i];
        qx[i] = qv.x; qy[i] = qv.y; qz[i] = qv.z; qxx[i] = qv.w;
        qorig[i] = SO[n0 + i];
        float tt = 0.053f * __expf(qxx[i] * (1.0f / 3.0f));  // ~32 expected passers
        t0[i] = tt > 3.f ? 3.f : tt;
        tlo[i] = 0.f; thi[i] = 0.f;             // 0 = unset bracket ends
        cnt[i] = 0;
        qdone[i] = false;
    }

    for (int attempt = 0; attempt < 40; ++attempt) {
        // wave-private window over active queries (uniform arithmetic)
        float zlo = 1e30f, zhi = -1e30f;
        bool anyact = false;
        #pragma unroll
        for (int i = 0; i < QPW; ++i) {
            if (qdone[i]) continue;
            anyact = true;
            float R = __fsqrt_rn(t0[i] + 1e-3f) + 1e-3f;
            zlo = fminf(zlo, qz[i] - R);
            zhi = fmaxf(zhi, qz[i] + R);
        }
        if (!anyact) break;
        int blo = zbin(zlo) - 1; if (blo < 0) blo = 0;
        int bhi = zbin(zhi) + 1; if (bhi > ZBINS - 1) bhi = ZBINS - 1;
        int lo = (int)BO[blo];
        int hi = (int)BO[bhi + 1];

        for (int p = lo; p < hi; p += 64) {
            int jj = p + lane;
            int j = jj < hi ? jj : hi - 1;
            float4 cc = S[j];
            int corig = SO[j];
            unsigned long long inbm = __ballot(jj < hi);
            #pragma unroll
            for (int i = 0; i < QPW; ++i) {
                if (qdone[i]) continue;                       // uniform branch
                float dot = __fmaf_rn(qz[i], cc.z, __fmaf_rn(qy[i], cc.y, __fmul_rn(qx[i], cc.x)));
                float dist = __fadd_rn(__fmaf_rn(-2.f, dot, qxx[i]), cc.w);
                unsigned long long mask = __ballot(dist <= t0[i]) & inbm;
                if (mask) {
                    bool pr = (dist <= t0[i]) && (jj < hi);
                    unsigned pos = cnt[i] + (unsigned)__popcll(mask & lt);
                    if (pr && pos < CAPQ) {
                        int db = __float_as_int(dist);
                        unsigned key = (unsigned)db ^ (unsigned)((db >> 31) | 0x80000000);
                        qbuf[(w * QPW + i) * CAPQ + pos] =
                            ((unsigned long long)key << 32) | (unsigned)corig;
                    }
                    cnt[i] += (unsigned)__popcll(mask);
                }
            }
        }
        #pragma unroll
        for (int i = 0; i < QPW; ++i) {
            if (qdone[i]) continue;
            if (cnt[i] < KN) {
                tlo[i] = t0[i];
                t0[i] = (thi[i] > 0.f) ? __fsqrt_rn(tlo[i] * thi[i]) : t0[i] * 2.0f;
                cnt[i] = 0;
            } else if (cnt[i] > CAPQ) {
                thi[i] = t0[i];
                t0[i] = (tlo[i] > 0.f) ? __fsqrt_rn(tlo[i] * thi[i]) : t0[i] * 0.5f;
                cnt[i] = 0;
            } else {
                qdone[i] = true; t0[i] = -1.0e30f;           // freeze stack
            }
        }
    }

    // ---- selection: counting-rank over the stack (no shuffle chains) ----
    #pragma unroll
    for (int i = 0; i < QPW; ++i) {
        unsigned tot = cnt[i] > CAPQ ? CAPQ : cnt[i];
        const unsigned long long* pb = qbuf + (w * QPW + i) * CAPQ;
        unsigned long long e0 = ((unsigned)lane < tot) ? pb[lane] : ~0ull;
        unsigned rank0 = 0;
        for (unsigned j = 0; j < tot; ++j) {
            unsigned long long v = pb[j];       // uniform addr -> LDS broadcast
            rank0 += (v < e0) ? 1u : 0u;
        }
        int obase = (b * NN + qorig[i]) * KN;
        if (((unsigned)lane < tot) && rank0 < KN)
            g_idx[obase + rank0] = (int)(e0 & 0xffffffffull);
    }
}

// ---------------- kernel 4: gather+max, rel, out = Wh' * rel ----------------
__global__ __launch_bounds__(256) void k_out(const float* __restrict__ Wh,
        float* __restrict__ out) {
    __shared__ float whs[CC * FE];
    int tid = threadIdx.x;
    for (int i = tid; i < CC * FE; i += 256) {
        int c = i >> 5, e = i & 31;
        float s = 0.f;
        #pragma unroll
        for (int m = 0; m < 4; ++m) s += Wh[c * 128 + m * 32 + e];
        whs[i] = s;
    }
    __syncthreads();
    int b = blockIdx.x >> 5;
    int n = ((blockIdx.x & 31) << 8) + tid;
    const int* ip = g_idx + (size_t)(b * NN + n) * KN;
    const float4* f0 = (const float4*)(g_feat0 + (size_t)b * NN * FE);
    float gmax[FE];
    #pragma unroll
    for (int e = 0; e < FE; ++e) gmax[e] = -__builtin_inff();
    for (int k = 0; k < KN; ++k) {
        int id = ip[k] & (NN - 1);      // defensive mask, no-op for valid idx
        const float4* row = f0 + (size_t)id * 8;
        #pragma unroll
        for (int e0 = 0; e0 < 8; ++e0) {
            float4 v = row[e0];
            gmax[e0 * 4 + 0] = fmaxf(gmax[e0 * 4 + 0], v.x);
            gmax[e0 * 4 + 1] = fmaxf(gmax[e0 * 4 + 1], v.y);
            gmax[e0 * 4 + 2] = fmaxf(gmax[e0 * 4 + 2], v.z);
            gmax[e0 * 4 + 3] = fmaxf(gmax[e0 * 4 + 3], v.w);
        }
    }
    const float4* selfr = f0 + (size_t)n * 8;
    float rel[FE];
    #pragma unroll
    for (int e0 = 0; e0 < 8; ++e0) {
        float4 v = selfr[e0];
        rel[e0 * 4 + 0] = gmax[e0 * 4 + 0] - v.x;
        rel[e0 * 4 + 1] = gmax[e0 * 4 + 1] - v.y;
        rel[e0 * 4 + 2] = gmax[e0 * 4 + 2] - v.z;
        rel[e0 * 4 + 3] = gmax[e0 * 4 + 3] - v.w;
    }
    float* op = out + (size_t)b * CC * NN + n;
    for (int c = 0; c < CC; ++c) {
        const float4* w4 = (const float4*)(whs + c * FE);
        float s = 0.f;
        #pragma unroll
        for (int e0 = 0; e0 < 8; ++e0) {
            float4 w = w4[e0];
            s = fmaf(w.x, rel[e0 * 4 + 0], s);
            s = fmaf(w.y, rel[e0 * 4 + 1], s);
            s = fmaf(w.z, rel[e0 * 4 + 2], s);
            s = fmaf(w.w, rel[e0 * 4 + 3], s);
        }
        op[(size_t)c * NN] = s;
    }
}

extern "C" void kernel_launch(void* const* d_in, const int* in_sizes, int n_in,
                              void* d_out, int out_size, void* d_ws, size_t ws_size,
                              hipStream_t stream) {
    const float* xyz   = (const float*)d_in[0];
    const float* feat  = (const float*)d_in[1];
    const float* gamma = (const float*)d_in[2];
    const float* beta  = (const float*)d_in[3];
    const float* Wg    = (const float*)d_in[4];
    const float* Wh    = (const float*)d_in[5];
    float* out = (float*)d_out;
    (void)d_ws; (void)ws_size;

    hipLaunchKernelGGL(k_bnstats, dim3(64),   dim3(1024), 0, stream, feat, gamma, beta);
    hipLaunchKernelGGL(k_zbin,    dim3(8),    dim3(1024), 0, stream, xyz);
    hipLaunchKernelGGL(k_feat0,   dim3(256),  dim3(256),  0, stream, feat, xyz, Wg);
    hipLaunchKernelGGL(k_knn,     dim3(2048), dim3(256),  0, stream);
    hipLaunchKernelGGL(k_out,     dim3(256),  dim3(256),  0, stream, Wh, out);
}

// Round 15
// 286.090 us; speedup vs baseline: 1.1294x; 1.1294x over previous
//
#include <hip/hip_runtime.h>
#include <math.h>

#define BB 8
#define NN 8192
#define CC 64
#define FE 32
#define KN 16
#define CP3 67
#define QPW 8                 // queries per wave (one per z-rank octile)
#define WPB 4                 // waves per block
#define CAPQ 64               // per-query stack (count-checked => exact)
#define ZBINS 256

// Device-global scratch (module .bss). All bytes written every launch before read.
__device__ float g_wsf[128];                  // scale[64], shift[64]
__device__ float g_feat0[BB * NN * FE];       // 8 MB
__device__ int   g_idx[BB * NN * KN];         // 4 MB
__device__ float4 g_sorted[BB * NN];          // z-bin-sorted {x,y,z,xx}
__device__ int    g_sorig[BB * NN];           // sorted -> original index
__device__ unsigned g_binoff[BB * (ZBINS + 1)];

// Identical in k_zbin and k_knn (same source => same bits; monotone in z).
__device__ __forceinline__ int zbin(float z) {
    int bi = (int)((z + 6.0f) * (64.0f / 3.0f));   // 256 bins over [-6,6]
    if (bi < 0) bi = 0;
    if (bi > ZBINS - 1) bi = ZBINS - 1;
    return bi;
}
// FROZEN reference xx (verified R5, XLA-CPU FMA contraction)
__device__ __forceinline__ float frz_xx(float x, float y, float z) {
    return __fmaf_rn(z, z, __fmaf_rn(y, y, __fmul_rn(x, x)));
}

// ---------------- kernel 1: BN stats -> scale/shift ----------------
__global__ __launch_bounds__(1024) void k_bnstats(const float* __restrict__ feat,
        const float* __restrict__ gamma, const float* __restrict__ beta) {
    int c = blockIdx.x;
    int tid = threadIdx.x;
    double s = 0.0, s2 = 0.0;
    for (int b = 0; b < BB; ++b) {
        const float* p = feat + ((size_t)(b * CC + c)) * NN;
        for (int n = tid; n < NN; n += 1024) {
            double v = (double)p[n];
            s += v; s2 += v * v;
        }
    }
    __shared__ double sh[1024], sh2[1024];
    sh[tid] = s; sh2[tid] = s2;
    __syncthreads();
    for (int off = 512; off > 0; off >>= 1) {
        if (tid < off) { sh[tid] += sh[tid + off]; sh2[tid] += sh2[tid + off]; }
        __syncthreads();
    }
    if (tid == 0) {
        double inv = 1.0 / (double)(BB * NN);
        double mean = sh[0] * inv;
        double var = sh2[0] * inv - mean * mean;
        float sc = gamma[c] * (float)(1.0 / sqrt(var + (double)1e-5f));
        g_wsf[c] = sc;
        g_wsf[64 + c] = beta[c] - sc * (float)mean;
    }
}

// ---------------- kernel 1b: z-binning (histogram + scatter) --------------
__global__ __launch_bounds__(1024) void k_zbin(const float* __restrict__ xyz) {
    __shared__ unsigned hist[ZBINS];
    __shared__ unsigned boff[ZBINS + 1];
    int b = blockIdx.x;
    int tid = threadIdx.x;
    if (tid < ZBINS) hist[tid] = 0;
    __syncthreads();
    const float* bx = xyz + (size_t)b * NN * 3;
    for (int n = tid; n < NN; n += 1024)
        atomicAdd(&hist[zbin(bx[n * 3 + 2])], 1u);
    __syncthreads();
    if (tid == 0) {
        unsigned s = 0;
        for (int i = 0; i < ZBINS; ++i) { boff[i] = s; s += hist[i]; }
        boff[ZBINS] = s;
    }
    __syncthreads();
    if (tid < ZBINS) hist[tid] = 0;            // reuse as cursors
    if (tid < ZBINS + 1) g_binoff[b * (ZBINS + 1) + tid] = boff[tid];
    __syncthreads();
    for (int n = tid; n < NN; n += 1024) {
        const float* p = bx + (size_t)n * 3;
        float x = p[0], y = p[1], z = p[2];
        unsigned pos = boff[zbin(z)] + atomicAdd(&hist[zbin(z)], 1u);
        g_sorted[(size_t)b * NN + pos] = make_float4(x, y, z, frz_xx(x, y, z));
        g_sorig[(size_t)b * NN + pos] = n;
    }
}

// ---------------- kernel 2: feat0 = Wg' * [feat;xyz] + bias0 ----------------
__global__ __launch_bounds__(256) void k_feat0(const float* __restrict__ feat,
        const float* __restrict__ xyz, const float* __restrict__ Wg) {
    __shared__ float wgs[CP3 * FE];
    __shared__ float bias0[FE];
    int tid = threadIdx.x;
    for (int i = tid; i < CP3 * FE; i += 256) {
        int c = i >> 5, e = i & 31;
        float w = Wg[e * CP3 + c];
        if (c < CC) w *= g_wsf[c];
        wgs[c * FE + e] = w;
    }
    if (tid < FE) {
        float sacc = 0.f;
        for (int c = 0; c < CC; ++c) sacc = fmaf(Wg[tid * CP3 + c], g_wsf[64 + c], sacc);
        bias0[tid] = sacc;
    }
    __syncthreads();
    int b = blockIdx.x >> 5;
    int n = ((blockIdx.x & 31) << 8) + tid;
    const float* pz = xyz + ((size_t)(b * NN + n)) * 3;
    float x = pz[0], y = pz[1], z = pz[2];

    float acc[FE];
    #pragma unroll
    for (int e = 0; e < FE; ++e) acc[e] = bias0[e];
    const float* fp = feat + (size_t)b * CC * NN + n;
    for (int c = 0; c < CC; ++c) {
        float v = fp[(size_t)c * NN];
        const float4* w4 = (const float4*)(wgs + c * FE);
        #pragma unroll
        for (int e0 = 0; e0 < 8; ++e0) {
            float4 w = w4[e0];
            acc[e0 * 4 + 0] = fmaf(w.x, v, acc[e0 * 4 + 0]);
            acc[e0 * 4 + 1] = fmaf(w.y, v, acc[e0 * 4 + 1]);
            acc[e0 * 4 + 2] = fmaf(w.z, v, acc[e0 * 4 + 2]);
            acc[e0 * 4 + 3] = fmaf(w.w, v, acc[e0 * 4 + 3]);
        }
    }
    #pragma unroll
    for (int d = 0; d < 3; ++d) {
        float v = (d == 0) ? x : ((d == 1) ? y : z);
        const float4* w4 = (const float4*)(wgs + (CC + d) * FE);
        #pragma unroll
        for (int e0 = 0; e0 < 8; ++e0) {
            float4 w = w4[e0];
            acc[e0 * 4 + 0] = fmaf(w.x, v, acc[e0 * 4 + 0]);
            acc[e0 * 4 + 1] = fmaf(w.y, v, acc[e0 * 4 + 1]);
            acc[e0 * 4 + 2] = fmaf(w.z, v, acc[e0 * 4 + 2]);
            acc[e0 * 4 + 3] = fmaf(w.w, v, acc[e0 * 4 + 3]);
        }
    }
    float4* outp = (float4*)(g_feat0 + ((size_t)(b * NN + n)) * FE);
    #pragma unroll
    for (int e0 = 0; e0 < 8; ++e0)
        outp[e0] = make_float4(acc[e0 * 4 + 0], acc[e0 * 4 + 1], acc[e0 * 4 + 2], acc[e0 * 4 + 3]);
}

// ---------------- kernel 3: stratified autonomous-wave KNN ---------------
// FROZEN reference arithmetic (verified R5):
//   dot  = fma(zq,zm, fma(yq,ym, xq*xm))
//   dist = fadd( fma(-2, dot, xx_q), xx_m )
// R15: each wave owns 8 queries STRATIFIED across z-rank (g + i*1024) and
// scans each query's OWN z-window sequentially. Per-wave work = one sample
// per z-octile => near-constant across waves; kills the R13/R14 drain tail
// (kernel time was set by fattest z-center wave, avg occupancy 17-20%).
// Per-query machinery unchanged and proven: gate+count-check (16<=cnt<=64),
// bracketed geometric bisection, counting-rank selection on u64
// (distbits|origidx) keys. Stack reused across the 8 queries -> 2 KB LDS.
__global__ __launch_bounds__(256) void k_knn() {
    __shared__ unsigned long long qbuf[WPB * CAPQ];   // 2 KB
    int tid = threadIdx.x;
    int lane = tid & 63;
    int w = tid >> 6;
    int wid = blockIdx.x * WPB + w;             // 0..8191
    int b = wid >> 10;                          // 1024 waves per batch
    int g = wid & 1023;                         // group index within batch
    const float4* S = g_sorted + (size_t)b * NN;
    const int* SO = g_sorig + (size_t)b * NN;
    const unsigned* BO = g_binoff + b * (ZBINS + 1);
    unsigned long long lt = (1ull << lane) - 1ull;
    unsigned long long* pb = qbuf + w * CAPQ;

    #pragma unroll 1
    for (int i = 0; i < QPW; ++i) {
        int qrank = g + (i << 10);              // stratum i sample
        float4 qv = S[qrank];
        float qx = qv.x, qy = qv.y, qz = qv.z, qxx = qv.w;
        int qorig = SO[qrank];
        float tt = 0.053f * __expf(qxx * (1.0f / 3.0f));   // ~32 expected passers
        float t0 = tt > 3.f ? 3.f : tt;
        float tlo = 0.f, thi = 0.f;             // bracket ends (0 = unset)
        unsigned cnt = 0;

        for (int attempt = 0; attempt < 40; ++attempt) {
            cnt = 0;
            float R = __fsqrt_rn(t0 + 1e-3f) + 1e-3f;
            int blo = zbin(qz - R) - 1; if (blo < 0) blo = 0;
            int bhi = zbin(qz + R) + 1; if (bhi > ZBINS - 1) bhi = ZBINS - 1;
            int lo = (int)BO[blo];
            int hi = (int)BO[bhi + 1];

            for (int p = lo; p < hi; p += 64) {
                int jj = p + lane;
                bool inb = jj < hi;
                int j = inb ? jj : hi - 1;
                float4 cc = S[j];
                float dot = __fmaf_rn(qz, cc.z, __fmaf_rn(qy, cc.y, __fmul_rn(qx, cc.x)));
                float dist = __fadd_rn(__fmaf_rn(-2.f, dot, qxx), cc.w);
                bool pr = (dist <= t0) && inb;
                unsigned long long mask = __ballot(pr);
                if (mask) {
                    unsigned pos = cnt + (unsigned)__popcll(mask & lt);
                    if (pr && pos < CAPQ) {
                        int corig = SO[j];      // loaded only for passers
                        int db = __float_as_int(dist);
                        unsigned key = (unsigned)db ^ (unsigned)((db >> 31) | 0x80000000);
                        pb[pos] = ((unsigned long long)key << 32) | (unsigned)corig;
                    }
                    cnt += (unsigned)__popcll(mask);
                }
            }
            if (cnt < KN) {
                tlo = t0;
                t0 = (thi > 0.f) ? __fsqrt_rn(tlo * thi) : t0 * 2.0f;
            } else if (cnt > CAPQ) {
                thi = t0;
                t0 = (tlo > 0.f) ? __fsqrt_rn(tlo * thi) : t0 * 0.5f;
            } else break;                        // accepted: stack = all passers
        }

        // ---- selection: counting-rank over the stack (CAPQ=64 -> 1/lane) ----
        unsigned tot = cnt > CAPQ ? CAPQ : cnt;
        unsigned long long e0 = ((unsigned)lane < tot) ? pb[lane] : ~0ull;
        unsigned rank0 = 0;
        for (unsigned jx = 0; jx < tot; ++jx) {
            unsigned long long v = pb[jx];      // uniform addr -> LDS broadcast
            rank0 += (v < e0) ? 1u : 0u;
        }
        if (((unsigned)lane < tot) && rank0 < KN)
            g_idx[(b * NN + qorig) * KN + rank0] = (int)(e0 & 0xffffffffull);
    }
}

// ---------------- kernel 4: gather+max, rel, out = Wh' * rel ----------------
__global__ __launch_bounds__(256) void k_out(const float* __restrict__ Wh,
        float* __restrict__ out) {
    __shared__ float whs[CC * FE];
    int tid = threadIdx.x;
    for (int i = tid; i < CC * FE; i += 256) {
        int c = i >> 5, e = i & 31;
        float s = 0.f;
        #pragma unroll
        for (int m = 0; m < 4; ++m) s += Wh[c * 128 + m * 32 + e];
        whs[i] = s;
    }
    __syncthreads();
    int b = blockIdx.x >> 5;
    int n = ((blockIdx.x & 31) << 8) + tid;
    const int* ip = g_idx + (size_t)(b * NN + n) * KN;
    const float4* f0 = (const float4*)(g_feat0 + (size_t)b * NN * FE);
    float gmax[FE];
    #pragma unroll
    for (int e = 0; e < FE; ++e) gmax[e] = -__builtin_inff();
    for (int k = 0; k < KN; ++k) {
        int id = ip[k] & (NN - 1);      // defensive mask, no-op for valid idx
        const float4* row = f0 + (size_t)id * 8;
        #pragma unroll
        for (int e0 = 0; e0 < 8; ++e0) {
            float4 v = row[e0];
            gmax[e0 * 4 + 0] = fmaxf(gmax[e0 * 4 + 0], v.x);
            gmax[e0 * 4 + 1] = fmaxf(gmax[e0 * 4 + 1], v.y);
            gmax[e0 * 4 + 2] = fmaxf(gmax[e0 * 4 + 2], v.z);
            gmax[e0 * 4 + 3] = fmaxf(gmax[e0 * 4 + 3], v.w);
        }
    }
    const float4* selfr = f0 + (size_t)n * 8;
    float rel[FE];
    #pragma unroll
    for (int e0 = 0; e0 < 8; ++e0) {
        float4 v = selfr[e0];
        rel[e0 * 4 + 0] = gmax[e0 * 4 + 0] - v.x;
        rel[e0 * 4 + 1] = gmax[e0 * 4 + 1] - v.y;
        rel[e0 * 4 + 2] = gmax[e0 * 4 + 2] - v.z;
        rel[e0 * 4 + 3] = gmax[e0 * 4 + 3] - v.w;
    }
    float* op = out + (size_t)b * CC * NN + n;
    for (int c = 0; c < CC; ++c) {
        const float4* w4 = (const float4*)(whs + c * FE);
        float s = 0.f;
        #pragma unroll
        for (int e0 = 0; e0 < 8; ++e0) {
            float4 w = w4[e0];
            s = fmaf(w.x, rel[e0 * 4 + 0], s);
            s = fmaf(w.y, rel[e0 * 4 + 1], s);
            s = fmaf(w.z, rel[e0 * 4 + 2], s);
            s = fmaf(w.w, rel[e0 * 4 + 3], s);
        }
        op[(size_t)c * NN] = s;
    }
}

extern "C" void kernel_launch(void* const* d_in, const int* in_sizes, int n_in,
                              void* d_out, int out_size, void* d_ws, size_t ws_size,
                              hipStream_t stream) {
    const float* xyz   = (const float*)d_in[0];
    const float* feat  = (const float*)d_in[1];
    const float* gamma = (const float*)d_in[2];
    const float* beta  = (const float*)d_in[3];
    const float* Wg    = (const float*)d_in[4];
    const float* Wh    = (const float*)d_in[5];
    float* out = (float*)d_out;
    (void)d_ws; (void)ws_size;

    hipLaunchKernelGGL(k_bnstats, dim3(64),   dim3(1024), 0, stream, feat, gamma, beta);
    hipLaunchKernelGGL(k_zbin,    dim3(8),    dim3(1024), 0, stream, xyz);
    hipLaunchKernelGGL(k_feat0,   dim3(256),  dim3(256),  0, stream, feat, xyz, Wg);
    hipLaunchKernelGGL(k_knn,     dim3(2048), dim3(256),  0, stream);
    hipLaunchKernelGGL(k_out,     dim3(256),  dim3(256),  0, stream, Wh, out);
}